// Round 8
// baseline (160.509 us; speedup 1.0000x reference)
//
#include <hip/hip_runtime.h>
#include <hip/hip_fp16.h>

// ---------------------------------------------------------------------------
// B=8, N=1024, F=320, H=5 (heads collapse: at = (Q·K^T)/8)
// R7: R6 (64x64 wave tiles, 16 MFMA/barrier) with the G4' grid bug fixed:
//     per-batch M=1024 -> grid y = 1024/BM = 4 (R6 used 32 -> 8x OOB on attn
//     reads + out stores -> page fault abort).
// Pipeline:
//   conv h -> fp16; transpose Wqk -> WqkT; transpose weight -> wTp (384 pad)
//   hWT GEMM (128x128): wTp @ h16^T -> hWT fp16 [384][8192]
//   G1' (256x64): h16 @ WqkT^T + bqk -> Q,K fp16 (deinterleave)
//   G2  (128x128): at = 0.125 * Q@K^T -> fp16
//   topk_softmax: exact 171st-largest (2-pass radix, 16-bit keys) -> attn fp16
//   G4' (256x64, grid (5,4,8)): out = attn @ hWT^T + bias (fp32)
// ---------------------------------------------------------------------------

typedef __attribute__((ext_vector_type(8))) _Float16 half8;
typedef __attribute__((ext_vector_type(4))) float f32x4;

// ---- stage a (nrow16*16) x 32 fp16 tile (row-major, ld elems) into LDS -----
__device__ __forceinline__ void stage_tile(const __half* g, __half* lds,
                                           int nrow16, int ld, int wave, int lane) {
    const int r = lane >> 2;
    const int c = (lane & 3) * 8;
    for (int i = wave; i < nrow16; i += 4) {
        const __half* src = g + (long)(i * 16 + r) * ld + c;
        __builtin_amdgcn_global_load_lds(
            (const __attribute__((address_space(1))) unsigned int*)src,
            (__attribute__((address_space(3))) unsigned int*)(lds + i * 512),
            16, 0, 0);
    }
}

// ---------------------------------------------------------------------------
// NT fp16 MFMA GEMM: C[m][n] = alpha * sum_k A[m][k]*B[n][k] (+epilogue)
// 256 threads = 4 waves in WM x WN grid; each wave owns a 64x64 tile
// (4x4 frags of 16x16x32 -> 16 MFMA per K-step). BM=WM*64, BN=WN*64, BK=32.
// EPI: 1 = +bqk, deinterleave -> Q fp16, K fp16   [G1']
//      2 = fp16 store                              [hWT]
//      3 = fp32 store + bias, batch-strided        [G4' -> out]
//      4 = fp16 store (alpha)                      [G2 -> at]
// ---------------------------------------------------------------------------
template <int WM, int WN, int EPI>
__global__ __launch_bounds__(256) void gemm_nt(
    const __half* __restrict__ A, const __half* __restrict__ B,
    void* __restrict__ C, void* __restrict__ C2,
    const float* __restrict__ bias,
    int K, int lda, int ldb, int ldc,
    long sA, long sB, long sC, float alpha)
{
    constexpr int BM = WM * 64;
    constexpr int BN = WN * 64;
    __shared__ __half smem[BM * 32 + BN * 32];
    __half* sA_ = smem;
    __half* sB_ = smem + BM * 32;

    const int tid  = threadIdx.x;
    const int lane = tid & 63;
    const int wave = tid >> 6;
    const int wm   = wave / WN;
    const int wn   = wave % WN;
    const int bz   = blockIdx.z;

    const __half* Ab = A + bz * sA + (long)blockIdx.y * BM * lda;
    const __half* Bb = B + bz * sB + (long)blockIdx.x * BN * ldb;

    f32x4 acc[4][4];
    #pragma unroll
    for (int i = 0; i < 4; ++i)
        #pragma unroll
        for (int j = 0; j < 4; ++j) acc[i][j] = (f32x4){0.f, 0.f, 0.f, 0.f};

    const int lrow = lane & 15;
    const int quad = lane >> 4;

    for (int k0 = 0; k0 < K; k0 += 32) {
        stage_tile(Ab + k0, sA_, BM / 16, lda, wave, lane);
        stage_tile(Bb + k0, sB_, BN / 16, ldb, wave, lane);
        __syncthreads();

        const __half* pA = sA_ + (wm * 64 + lrow) * 32 + quad * 8;
        const __half* pB = sB_ + (wn * 64 + lrow) * 32 + quad * 8;
        half8 ah[4], bh[4];
        #pragma unroll
        for (int mt = 0; mt < 4; ++mt) ah[mt] = *(const half8*)(pA + mt * 512);
        #pragma unroll
        for (int nt = 0; nt < 4; ++nt) bh[nt] = *(const half8*)(pB + nt * 512);
        #pragma unroll
        for (int mt = 0; mt < 4; ++mt)
            #pragma unroll
            for (int nt = 0; nt < 4; ++nt)
                acc[mt][nt] = __builtin_amdgcn_mfma_f32_16x16x32_f16(
                    ah[mt], bh[nt], acc[mt][nt], 0, 0, 0);
        __syncthreads();
    }

    // epilogue: C[row][col]; col = lane&15 within 16-tile, row = quad*4 + r
    const int row_base = blockIdx.y * BM + wm * 64;
    const int col_base = blockIdx.x * BN + wn * 64;
    #pragma unroll
    for (int mt = 0; mt < 4; ++mt)
        #pragma unroll
        for (int nt = 0; nt < 4; ++nt)
            #pragma unroll
            for (int r = 0; r < 4; ++r) {
                const int row = row_base + mt * 16 + quad * 4 + r;
                const int col = col_base + nt * 16 + lrow;
                const float v = acc[mt][nt][r];
                if (EPI == 1) {
                    const float val = v + bias[col];
                    const long idx = (long)row * 320 + (col >> 1);
                    if (col & 1) ((__half*)C2)[idx] = __float2half(val);
                    else         ((__half*)C)[idx]  = __float2half(val);
                } else if (EPI == 2) {
                    ((__half*)C)[(long)row * ldc + col] = __float2half(v);
                } else if (EPI == 3) {
                    ((float*)C)[bz * sC + (long)row * ldc + col] = v + bias[col];
                } else {  // EPI == 4
                    ((__half*)C)[bz * sC + (long)row * ldc + col] =
                        __float2half(alpha * v);
                }
            }
}

// ---- elementwise convert fp32 -> fp16 --------------------------------------
__global__ __launch_bounds__(256) void conv_f16(const float4* __restrict__ src,
                                                ushort4* __restrict__ dst)
{
    const int i = blockIdx.x * 256 + threadIdx.x;
    const float4 v = src[i];
    ushort4 o;
    o.x = __half_as_ushort(__float2half(v.x));
    o.y = __half_as_ushort(__float2half(v.y));
    o.z = __half_as_ushort(__float2half(v.z));
    o.w = __half_as_ushort(__float2half(v.w));
    dst[i] = o;
}

// ---- 32x32 tiled transpose fp32 -> fp16 ------------------------------------
__global__ __launch_bounds__(256) void transpose_f16(
    const float* __restrict__ src, __half* __restrict__ dst, int ldS, int ldT)
{
    __shared__ float t[32][33];
    const int c0 = blockIdx.x * 32, r0 = blockIdx.y * 32;
    const int lx = threadIdx.x & 31, ly = threadIdx.x >> 5;
    #pragma unroll
    for (int i = 0; i < 4; ++i)
        t[ly + 8 * i][lx] = src[(long)(r0 + ly + 8 * i) * ldS + c0 + lx];
    __syncthreads();
    #pragma unroll
    for (int i = 0; i < 4; ++i)
        dst[(long)(c0 + ly + 8 * i) * ldT + r0 + lx] = __float2half(t[lx][ly + 8 * i]);
}

// ---------------------------------------------------------------------------
// Exact 171st-largest per row of 1024 fp16 values: 2-pass radix select on
// 16-bit order-preserving keys. One wave per row (4 rows / block).
// ---------------------------------------------------------------------------
__global__ __launch_bounds__(256) void topk_softmax(const __half* __restrict__ at,
                                                    __half* __restrict__ attn)
{
    __shared__ int hist[4][256];
    const int lane = threadIdx.x & 63;
    const int wave = threadIdx.x >> 6;
    const long row = (long)blockIdx.x * 4 + wave;

    unsigned short vs[16];
    {
        const uint4* p = (const uint4*)(at + row * 1024 + lane * 16);
        *(uint4*)&vs[0] = p[0];
        *(uint4*)&vs[8] = p[1];
    }

    unsigned key[16];
    #pragma unroll
    for (int i = 0; i < 16; ++i) {
        const unsigned u = vs[i];
        key[i] = (u & 0x8000u) ? ((~u) & 0xFFFFu) : (u | 0x8000u);
    }

    unsigned prefix = 0, pmask = 0;
    int kk = 171;

    #pragma unroll
    for (int pass = 0; pass < 2; ++pass) {
        const int shift = 8 - 8 * pass;
        *(int4*)&hist[wave][lane * 4] = make_int4(0, 0, 0, 0);
        __syncthreads();
        #pragma unroll
        for (int i = 0; i < 16; ++i) {
            if ((key[i] & pmask) == prefix)
                atomicAdd(&hist[wave][(key[i] >> shift) & 255], 1);
        }
        __syncthreads();
        const int4 hh = *(const int4*)&hist[wave][lane * 4];
        const int s = hh.x + hh.y + hh.z + hh.w;
        int suf = s;
        #pragma unroll
        for (int off = 1; off < 64; off <<= 1) {
            const int o = __shfl_down(suf, off);
            if (lane + off < 64) suf += o;
        }
        const int cgt3 = suf - s;
        const int cgt2 = cgt3 + hh.w;
        const int cgt1 = cgt2 + hh.z;
        const int cgt0 = cgt1 + hh.y;
        int pick = 0x7FFFFFFF;
        if (cgt3 < kk && kk <= cgt3 + hh.w) pick = ((4 * lane + 3) << 16) | (kk - cgt3);
        if (cgt2 < kk && kk <= cgt2 + hh.z) pick = ((4 * lane + 2) << 16) | (kk - cgt2);
        if (cgt1 < kk && kk <= cgt1 + hh.y) pick = ((4 * lane + 1) << 16) | (kk - cgt1);
        if (cgt0 < kk && kk <= cgt0 + hh.x) pick = ((4 * lane + 0) << 16) | (kk - cgt0);
        #pragma unroll
        for (int off = 32; off > 0; off >>= 1) pick = min(pick, __shfl_xor(pick, off));
        const unsigned digit = (unsigned)(pick >> 16);
        kk = pick & 0xFFFF;
        prefix |= digit << shift;
        pmask  |= 0xFFu << shift;
        if (pass == 0) __syncthreads();
    }

    const unsigned short tu = (prefix & 0x8000u) ? (unsigned short)(prefix & 0x7FFFu)
                                                 : (unsigned short)((~prefix) & 0xFFFFu);
    const float thr = __half2float(__ushort_as_half(tu));

    float lg[16];
    float mx = -3.4e38f;
    #pragma unroll
    for (int i = 0; i < 16; ++i) {
        const float v = __half2float(__ushort_as_half(vs[i]));
        const float a = (v < thr) ? -1e-7f : v;
        lg[i] = a * (1.0f / 0.3f);
        mx = fmaxf(mx, lg[i]);
    }
    #pragma unroll
    for (int off = 32; off > 0; off >>= 1) mx = fmaxf(mx, __shfl_xor(mx, off));

    float e[16];
    float sum = 0.f;
    #pragma unroll
    for (int i = 0; i < 16; ++i) { e[i] = __expf(lg[i] - mx); sum += e[i]; }
    #pragma unroll
    for (int off = 32; off > 0; off >>= 1) sum += __shfl_xor(sum, off);
    const float inv = 1.0f / sum;

    unsigned short os[16];
    #pragma unroll
    for (int i = 0; i < 16; ++i) os[i] = __half_as_ushort(__float2half(e[i] * inv));
    uint4* q = (uint4*)(attn + row * 1024 + lane * 16);
    q[0] = *(const uint4*)&os[0];
    q[1] = *(const uint4*)&os[8];
}

extern "C" void kernel_launch(void* const* d_in, const int* in_sizes, int n_in,
                              void* d_out, int out_size, void* d_ws, size_t ws_size,
                              hipStream_t stream) {
    (void)in_sizes; (void)n_in; (void)out_size; (void)ws_size;

    const float* h      = (const float*)d_in[0];  // 8x1024x320
    const float* Wqk    = (const float*)d_in[1];  // 320x640
    const float* bqk    = (const float*)d_in[2];  // 640
    const float* weight = (const float*)d_in[3];  // 320x320
    const float* bias   = (const float*)d_in[4];  // 320
    float* out = (float*)d_out;                   // 8192x320

    // workspace layout
    char* p = (char*)d_ws;
    __half* at   = (__half*)p; p += 8388608L * 2;        // 16 MB
    __half* attn = (__half*)p; p += 8388608L * 2;        // 16 MB
    __half* h16  = (__half*)p; p += 2621440L * 2;        // 5 MB
    __half* Q    = (__half*)p; p += 2621440L * 2;        // 5 MB
    __half* Kb   = (__half*)p; p += 2621440L * 2;        // 5 MB
    __half* WqkT = (__half*)p; p += 640L * 320 * 2;      // 400 KB
    __half* wTp  = (__half*)p; p += 384L * 320 * 2;      // padded to 384 rows
    __half* hWT  = (__half*)p; p += 384L * 8192 * 2;     // 6 MB (384 rows incl pad)

    // --- prep: h -> fp16; WqkT [640][320]; wTp [384pad][320] ---
    conv_f16<<<2560, 256, 0, stream>>>((const float4*)h, (ushort4*)h16);
    transpose_f16<<<dim3(20, 10, 1), 256, 0, stream>>>(Wqk, WqkT, 640, 320);
    transpose_f16<<<dim3(10, 10, 1), 256, 0, stream>>>(weight, wTp, 320, 320);

    // --- hWT = wTp @ h16^T : [384pad][320] x [8192][320]^T -> fp16 [384][8192]
    gemm_nt<2, 2, 2><<<dim3(64, 3, 1), 256, 0, stream>>>(
        wTp, h16, hWT, nullptr, nullptr,
        320, 320, 320, 8192, 0, 0, 0, 1.0f);

    // --- G1': qk = h16 @ WqkT^T + bqk -> Q,K fp16 (deinterleave) ---
    gemm_nt<4, 1, 1><<<dim3(10, 32, 1), 256, 0, stream>>>(
        h16, WqkT, Q, Kb, bqk,
        320, 320, 320, 0, 0, 0, 0, 1.0f);

    // --- G2: at = 0.125 * Q@K^T (fp16 out) ---
    gemm_nt<2, 2, 4><<<dim3(8, 8, 8), 256, 0, stream>>>(
        Q, Kb, at, nullptr, nullptr,
        320, 320, 320, 1024, 327680, 327680, 1048576, 0.125f);

    // --- topk + softmax -> attn (fp16); one wave per row ---
    topk_softmax<<<2048, 256, 0, stream>>>(at, attn);

    // --- G4': out = attn @ hWT^T + bias (fp32); per-batch M=1024 -> grid y=4
    gemm_nt<4, 1, 3><<<dim3(5, 4, 8), 256, 0, stream>>>(
        attn, hWT, out, nullptr, bias,
        1024, 1024, 8192, 320, 1048576, 1024, 327680, 1.0f);
}

// Round 9
// 156.658 us; speedup vs baseline: 1.0246x; 1.0246x over previous
//
#include <hip/hip_runtime.h>
#include <hip/hip_fp16.h>

// ---------------------------------------------------------------------------
// B=8, N=1024, F=320, H=5 (heads collapse: at = (Q·K^T)/8)
// R8: XOR-swizzled LDS staging to kill the 8-way bank conflict on every
//     fragment ds_read_b128 (bank start 16*(row&1)+4*quad covered only 2
//     groups per 16-lane quarter). Staging source chunk = (lane&3)^((lane>>3)&3);
//     read slot = quad^((row>>1)&3). Numerics identical to R7.
// Pipeline:
//   conv h -> fp16; transpose Wqk -> WqkT; transpose weight -> wTp (384 pad)
//   hWT GEMM (128x128): wTp @ h16^T -> hWT fp16 [384][8192]
//   G1' (256x64): h16 @ WqkT^T + bqk -> Q,K fp16 (deinterleave)
//   G2  (128x128): at = 0.125 * Q@K^T -> fp16
//   topk_softmax: exact 171st-largest (2-pass radix, 16-bit keys) -> attn fp16
//   G4' (256x64, grid (5,4,8)): out = attn @ hWT^T + bias (fp32)
// ---------------------------------------------------------------------------

typedef __attribute__((ext_vector_type(8))) _Float16 half8;
typedef __attribute__((ext_vector_type(4))) float f32x4;

// ---- stage a (nrow16*16) x 32 fp16 tile into LDS, K-chunk XOR-swizzled -----
// LDS slot (row r, slot j) holds global chunk j ^ ((r>>1)&3). The LDS
// destination of global_load_lds is the mandatory contiguous lane*16B; only
// the global SOURCE is permuted (per-row chunk rotation), so global reads
// stay 64B-segment coalesced.
__device__ __forceinline__ void stage_tile(const __half* g, __half* lds,
                                           int nrow16, int ld, int wave, int lane) {
    const int r = lane >> 2;
    const int c = ((lane & 3) ^ ((lane >> 3) & 3)) * 8;  // swizzled chunk
    for (int i = wave; i < nrow16; i += 4) {
        const __half* src = g + (long)(i * 16 + r) * ld + c;
        __builtin_amdgcn_global_load_lds(
            (const __attribute__((address_space(1))) unsigned int*)src,
            (__attribute__((address_space(3))) unsigned int*)(lds + i * 512),
            16, 0, 0);
    }
}

// ---------------------------------------------------------------------------
// NT fp16 MFMA GEMM: C[m][n] = alpha * sum_k A[m][k]*B[n][k] (+epilogue)
// 256 threads = 4 waves in WM x WN grid; each wave owns a 64x64 tile
// (4x4 frags of 16x16x32 -> 16 MFMA per K-step). BM=WM*64, BN=WN*64, BK=32.
// EPI: 1 = +bqk, deinterleave -> Q fp16, K fp16   [G1']
//      2 = fp16 store                              [hWT]
//      3 = fp32 store + bias, batch-strided        [G4' -> out]
//      4 = fp16 store (alpha)                      [G2 -> at]
// ---------------------------------------------------------------------------
template <int WM, int WN, int EPI>
__global__ __launch_bounds__(256) void gemm_nt(
    const __half* __restrict__ A, const __half* __restrict__ B,
    void* __restrict__ C, void* __restrict__ C2,
    const float* __restrict__ bias,
    int K, int lda, int ldb, int ldc,
    long sA, long sB, long sC, float alpha)
{
    constexpr int BM = WM * 64;
    constexpr int BN = WN * 64;
    __shared__ __half smem[BM * 32 + BN * 32];
    __half* sA_ = smem;
    __half* sB_ = smem + BM * 32;

    const int tid  = threadIdx.x;
    const int lane = tid & 63;
    const int wave = tid >> 6;
    const int wm   = wave / WN;
    const int wn   = wave % WN;
    const int bz   = blockIdx.z;

    const __half* Ab = A + bz * sA + (long)blockIdx.y * BM * lda;
    const __half* Bb = B + bz * sB + (long)blockIdx.x * BN * ldb;

    f32x4 acc[4][4];
    #pragma unroll
    for (int i = 0; i < 4; ++i)
        #pragma unroll
        for (int j = 0; j < 4; ++j) acc[i][j] = (f32x4){0.f, 0.f, 0.f, 0.f};

    const int lrow = lane & 15;
    const int quad = lane >> 4;
    // read-side swizzle: chunk quad of row lrow lives at slot quad^((lrow>>1)&3)
    const int swz = (quad ^ ((lrow >> 1) & 3)) * 8;

    for (int k0 = 0; k0 < K; k0 += 32) {
        stage_tile(Ab + k0, sA_, BM / 16, lda, wave, lane);
        stage_tile(Bb + k0, sB_, BN / 16, ldb, wave, lane);
        __syncthreads();

        const __half* pA = sA_ + (wm * 64 + lrow) * 32 + swz;
        const __half* pB = sB_ + (wn * 64 + lrow) * 32 + swz;
        half8 ah[4], bh[4];
        #pragma unroll
        for (int mt = 0; mt < 4; ++mt) ah[mt] = *(const half8*)(pA + mt * 512);
        #pragma unroll
        for (int nt = 0; nt < 4; ++nt) bh[nt] = *(const half8*)(pB + nt * 512);
        #pragma unroll
        for (int mt = 0; mt < 4; ++mt)
            #pragma unroll
            for (int nt = 0; nt < 4; ++nt)
                acc[mt][nt] = __builtin_amdgcn_mfma_f32_16x16x32_f16(
                    ah[mt], bh[nt], acc[mt][nt], 0, 0, 0);
        __syncthreads();
    }

    // epilogue: C[row][col]; col = lane&15 within 16-tile, row = quad*4 + r
    const int row_base = blockIdx.y * BM + wm * 64;
    const int col_base = blockIdx.x * BN + wn * 64;
    #pragma unroll
    for (int mt = 0; mt < 4; ++mt)
        #pragma unroll
        for (int nt = 0; nt < 4; ++nt)
            #pragma unroll
            for (int r = 0; r < 4; ++r) {
                const int row = row_base + mt * 16 + quad * 4 + r;
                const int col = col_base + nt * 16 + lrow;
                const float v = acc[mt][nt][r];
                if (EPI == 1) {
                    const float val = v + bias[col];
                    const long idx = (long)row * 320 + (col >> 1);
                    if (col & 1) ((__half*)C2)[idx] = __float2half(val);
                    else         ((__half*)C)[idx]  = __float2half(val);
                } else if (EPI == 2) {
                    ((__half*)C)[(long)row * ldc + col] = __float2half(v);
                } else if (EPI == 3) {
                    ((float*)C)[bz * sC + (long)row * ldc + col] = v + bias[col];
                } else {  // EPI == 4
                    ((__half*)C)[bz * sC + (long)row * ldc + col] =
                        __float2half(alpha * v);
                }
            }
}

// ---- elementwise convert fp32 -> fp16 --------------------------------------
__global__ __launch_bounds__(256) void conv_f16(const float4* __restrict__ src,
                                                ushort4* __restrict__ dst)
{
    const int i = blockIdx.x * 256 + threadIdx.x;
    const float4 v = src[i];
    ushort4 o;
    o.x = __half_as_ushort(__float2half(v.x));
    o.y = __half_as_ushort(__float2half(v.y));
    o.z = __half_as_ushort(__float2half(v.z));
    o.w = __half_as_ushort(__float2half(v.w));
    dst[i] = o;
}

// ---- 32x32 tiled transpose fp32 -> fp16 ------------------------------------
__global__ __launch_bounds__(256) void transpose_f16(
    const float* __restrict__ src, __half* __restrict__ dst, int ldS, int ldT)
{
    __shared__ float t[32][33];
    const int c0 = blockIdx.x * 32, r0 = blockIdx.y * 32;
    const int lx = threadIdx.x & 31, ly = threadIdx.x >> 5;
    #pragma unroll
    for (int i = 0; i < 4; ++i)
        t[ly + 8 * i][lx] = src[(long)(r0 + ly + 8 * i) * ldS + c0 + lx];
    __syncthreads();
    #pragma unroll
    for (int i = 0; i < 4; ++i)
        dst[(long)(c0 + ly + 8 * i) * ldT + r0 + lx] = __float2half(t[lx][ly + 8 * i]);
}

// ---------------------------------------------------------------------------
// Exact 171st-largest per row of 1024 fp16 values: 2-pass radix select on
// 16-bit order-preserving keys. One wave per row (4 rows / block).
// ---------------------------------------------------------------------------
__global__ __launch_bounds__(256) void topk_softmax(const __half* __restrict__ at,
                                                    __half* __restrict__ attn)
{
    __shared__ int hist[4][256];
    const int lane = threadIdx.x & 63;
    const int wave = threadIdx.x >> 6;
    const long row = (long)blockIdx.x * 4 + wave;

    unsigned short vs[16];
    {
        const uint4* p = (const uint4*)(at + row * 1024 + lane * 16);
        *(uint4*)&vs[0] = p[0];
        *(uint4*)&vs[8] = p[1];
    }

    unsigned key[16];
    #pragma unroll
    for (int i = 0; i < 16; ++i) {
        const unsigned u = vs[i];
        key[i] = (u & 0x8000u) ? ((~u) & 0xFFFFu) : (u | 0x8000u);
    }

    unsigned prefix = 0, pmask = 0;
    int kk = 171;

    #pragma unroll
    for (int pass = 0; pass < 2; ++pass) {
        const int shift = 8 - 8 * pass;
        *(int4*)&hist[wave][lane * 4] = make_int4(0, 0, 0, 0);
        __syncthreads();
        #pragma unroll
        for (int i = 0; i < 16; ++i) {
            if ((key[i] & pmask) == prefix)
                atomicAdd(&hist[wave][(key[i] >> shift) & 255], 1);
        }
        __syncthreads();
        const int4 hh = *(const int4*)&hist[wave][lane * 4];
        const int s = hh.x + hh.y + hh.z + hh.w;
        int suf = s;
        #pragma unroll
        for (int off = 1; off < 64; off <<= 1) {
            const int o = __shfl_down(suf, off);
            if (lane + off < 64) suf += o;
        }
        const int cgt3 = suf - s;
        const int cgt2 = cgt3 + hh.w;
        const int cgt1 = cgt2 + hh.z;
        const int cgt0 = cgt1 + hh.y;
        int pick = 0x7FFFFFFF;
        if (cgt3 < kk && kk <= cgt3 + hh.w) pick = ((4 * lane + 3) << 16) | (kk - cgt3);
        if (cgt2 < kk && kk <= cgt2 + hh.z) pick = ((4 * lane + 2) << 16) | (kk - cgt2);
        if (cgt1 < kk && kk <= cgt1 + hh.y) pick = ((4 * lane + 1) << 16) | (kk - cgt1);
        if (cgt0 < kk && kk <= cgt0 + hh.x) pick = ((4 * lane + 0) << 16) | (kk - cgt0);
        #pragma unroll
        for (int off = 32; off > 0; off >>= 1) pick = min(pick, __shfl_xor(pick, off));
        const unsigned digit = (unsigned)(pick >> 16);
        kk = pick & 0xFFFF;
        prefix |= digit << shift;
        pmask  |= 0xFFu << shift;
        if (pass == 0) __syncthreads();
    }

    const unsigned short tu = (prefix & 0x8000u) ? (unsigned short)(prefix & 0x7FFFu)
                                                 : (unsigned short)((~prefix) & 0xFFFFu);
    const float thr = __half2float(__ushort_as_half(tu));

    float lg[16];
    float mx = -3.4e38f;
    #pragma unroll
    for (int i = 0; i < 16; ++i) {
        const float v = __half2float(__ushort_as_half(vs[i]));
        const float a = (v < thr) ? -1e-7f : v;
        lg[i] = a * (1.0f / 0.3f);
        mx = fmaxf(mx, lg[i]);
    }
    #pragma unroll
    for (int off = 32; off > 0; off >>= 1) mx = fmaxf(mx, __shfl_xor(mx, off));

    float e[16];
    float sum = 0.f;
    #pragma unroll
    for (int i = 0; i < 16; ++i) { e[i] = __expf(lg[i] - mx); sum += e[i]; }
    #pragma unroll
    for (int off = 32; off > 0; off >>= 1) sum += __shfl_xor(sum, off);
    const float inv = 1.0f / sum;

    unsigned short os[16];
    #pragma unroll
    for (int i = 0; i < 16; ++i) os[i] = __half_as_ushort(__float2half(e[i] * inv));
    uint4* q = (uint4*)(attn + row * 1024 + lane * 16);
    q[0] = *(const uint4*)&os[0];
    q[1] = *(const uint4*)&os[8];
}

extern "C" void kernel_launch(void* const* d_in, const int* in_sizes, int n_in,
                              void* d_out, int out_size, void* d_ws, size_t ws_size,
                              hipStream_t stream) {
    (void)in_sizes; (void)n_in; (void)out_size; (void)ws_size;

    const float* h      = (const float*)d_in[0];  // 8x1024x320
    const float* Wqk    = (const float*)d_in[1];  // 320x640
    const float* bqk    = (const float*)d_in[2];  // 640
    const float* weight = (const float*)d_in[3];  // 320x320
    const float* bias   = (const float*)d_in[4];  // 320
    float* out = (float*)d_out;                   // 8192x320

    // workspace layout
    char* p = (char*)d_ws;
    __half* at   = (__half*)p; p += 8388608L * 2;        // 16 MB
    __half* attn = (__half*)p; p += 8388608L * 2;        // 16 MB
    __half* h16  = (__half*)p; p += 2621440L * 2;        // 5 MB
    __half* Q    = (__half*)p; p += 2621440L * 2;        // 5 MB
    __half* Kb   = (__half*)p; p += 2621440L * 2;        // 5 MB
    __half* WqkT = (__half*)p; p += 640L * 320 * 2;      // 400 KB
    __half* wTp  = (__half*)p; p += 384L * 320 * 2;      // padded to 384 rows
    __half* hWT  = (__half*)p; p += 384L * 8192 * 2;     // 6 MB (384 rows incl pad)

    // --- prep: h -> fp16; WqkT [640][320]; wTp [384pad][320] ---
    conv_f16<<<2560, 256, 0, stream>>>((const float4*)h, (ushort4*)h16);
    transpose_f16<<<dim3(20, 10, 1), 256, 0, stream>>>(Wqk, WqkT, 640, 320);
    transpose_f16<<<dim3(10, 10, 1), 256, 0, stream>>>(weight, wTp, 320, 320);

    // --- hWT = wTp @ h16^T : [384pad][320] x [8192][320]^T -> fp16 [384][8192]
    gemm_nt<2, 2, 2><<<dim3(64, 3, 1), 256, 0, stream>>>(
        wTp, h16, hWT, nullptr, nullptr,
        320, 320, 320, 8192, 0, 0, 0, 1.0f);

    // --- G1': qk = h16 @ WqkT^T + bqk -> Q,K fp16 (deinterleave) ---
    gemm_nt<4, 1, 1><<<dim3(10, 32, 1), 256, 0, stream>>>(
        h16, WqkT, Q, Kb, bqk,
        320, 320, 320, 0, 0, 0, 0, 1.0f);

    // --- G2: at = 0.125 * Q@K^T (fp16 out) ---
    gemm_nt<2, 2, 4><<<dim3(8, 8, 8), 256, 0, stream>>>(
        Q, Kb, at, nullptr, nullptr,
        320, 320, 320, 1024, 327680, 327680, 1048576, 0.125f);

    // --- topk + softmax -> attn (fp16); one wave per row ---
    topk_softmax<<<2048, 256, 0, stream>>>(at, attn);

    // --- G4': out = attn @ hWT^T + bias (fp32); per-batch M=1024 -> grid y=4
    gemm_nt<4, 1, 3><<<dim3(5, 4, 8), 256, 0, stream>>>(
        attn, hWT, out, nullptr, bias,
        1024, 1024, 8192, 320, 1048576, 1024, 327680, 1.0f);
}

// Round 10
// 145.978 us; speedup vs baseline: 1.0995x; 1.0732x over previous
//
#include <hip/hip_runtime.h>
#include <hip/hip_fp16.h>

// ---------------------------------------------------------------------------
// B=8, N=1024, F=320, H=5 (heads collapse: at = (Q·K^T)/8)
// R9: explicit LDS DOUBLE-BUFFER in all GEMMs. All dispatches run at 1-2
//     blocks/CU (no TLP), so per-iter staging latency is the critical path;
//     dbuf overlaps next tile's global_load_lds with current MFMA.
//     Also: 3 prep kernels fused into 1 launch. Numerics identical to R8.
// Pipeline:
//   prep_all: h->fp16 | Wqk^T fp16 | weight^T fp16 (one launch)
//   hWT GEMM (128x128): wTp @ h16^T -> hWT fp16 [384][8192]
//   G1' (256x64): h16 @ WqkT^T + bqk -> Q,K fp16 (deinterleave)
//   G2  (128x128): at = 0.125 * Q@K^T -> fp16
//   topk_softmax: exact 171st-largest (2-pass radix, 16-bit keys) -> attn fp16
//   G4' (256x64, grid (5,4,8)): out = attn @ hWT^T + bias (fp32)
// ---------------------------------------------------------------------------

typedef __attribute__((ext_vector_type(8))) _Float16 half8;
typedef __attribute__((ext_vector_type(4))) float f32x4;

// ---- stage a (nrow16*16) x 32 fp16 tile into LDS, K-chunk XOR-swizzled -----
// LDS slot (row r, slot j) holds global chunk j ^ ((r>>1)&3). global_load_lds
// LDS dest is the mandatory contiguous lane*16B; only the global SOURCE is
// permuted, so global reads stay 64B-segment coalesced.
__device__ __forceinline__ void stage_tile(const __half* g, __half* lds,
                                           int nrow16, int ld, int wave, int lane) {
    const int r = lane >> 2;
    const int c = ((lane & 3) ^ ((lane >> 3) & 3)) * 8;  // swizzled chunk
    for (int i = wave; i < nrow16; i += 4) {
        const __half* src = g + (long)(i * 16 + r) * ld + c;
        __builtin_amdgcn_global_load_lds(
            (const __attribute__((address_space(1))) unsigned int*)src,
            (__attribute__((address_space(3))) unsigned int*)(lds + i * 512),
            16, 0, 0);
    }
}

// ---------------------------------------------------------------------------
// NT fp16 MFMA GEMM, double-buffered: C[m][n] = alpha*sum_k A[m][k]*B[n][k]
// 256 threads = 4 waves in WM x WN grid; each wave owns a 64x64 tile
// (4x4 frags of 16x16x32 -> 16 MFMA per K-step). BM=WM*64, BN=WN*64, BK=32.
// K-loop: sync (drains buf(k) loads) -> issue buf(k+1) loads -> MFMA buf(k).
// EPI: 1 = +bqk, deinterleave -> Q fp16, K fp16   [G1']
//      2 = fp16 store                              [hWT]
//      3 = fp32 store + bias, batch-strided        [G4' -> out]
//      4 = fp16 store (alpha)                      [G2 -> at]
// ---------------------------------------------------------------------------
template <int WM, int WN, int EPI>
__global__ __launch_bounds__(256) void gemm_nt(
    const __half* __restrict__ A, const __half* __restrict__ B,
    void* __restrict__ C, void* __restrict__ C2,
    const float* __restrict__ bias,
    int K, int lda, int ldb, int ldc,
    long sA, long sB, long sC, float alpha)
{
    constexpr int BM = WM * 64;
    constexpr int BN = WN * 64;
    constexpr int BUF = BM * 32 + BN * 32;
    __shared__ __half smem[2 * BUF];

    const int tid  = threadIdx.x;
    const int lane = tid & 63;
    const int wave = tid >> 6;
    const int wm   = wave / WN;
    const int wn   = wave % WN;
    const int bz   = blockIdx.z;

    const __half* Ab = A + bz * sA + (long)blockIdx.y * BM * lda;
    const __half* Bb = B + bz * sB + (long)blockIdx.x * BN * ldb;

    f32x4 acc[4][4];
    #pragma unroll
    for (int i = 0; i < 4; ++i)
        #pragma unroll
        for (int j = 0; j < 4; ++j) acc[i][j] = (f32x4){0.f, 0.f, 0.f, 0.f};

    const int lrow = lane & 15;
    const int quad = lane >> 4;
    // read-side swizzle: chunk quad of row lrow lives at slot quad^((lrow>>1)&3)
    const int swz = (quad ^ ((lrow >> 1) & 3)) * 8;

    const int nIter = K >> 5;

    // prologue: stage iter 0 into buffer 0
    stage_tile(Ab, smem, BM / 16, lda, wave, lane);
    stage_tile(Bb, smem + BM * 32, BN / 16, ldb, wave, lane);

    for (int it = 0; it < nIter; ++it) {
        __syncthreads();  // drains buf(it) loads (compiler vmcnt before barrier)

        // issue next tile's loads into the other buffer NOW; they fly
        // while we do MFMA on the current buffer.
        if (it + 1 < nIter) {
            __half* nb = smem + ((it + 1) & 1) * BUF;
            const int k1 = (it + 1) << 5;
            stage_tile(Ab + k1, nb, BM / 16, lda, wave, lane);
            stage_tile(Bb + k1, nb + BM * 32, BN / 16, ldb, wave, lane);
        }

        const __half* buf = smem + (it & 1) * BUF;
        const __half* pA = buf + (wm * 64 + lrow) * 32 + swz;
        const __half* pB = buf + BM * 32 + (wn * 64 + lrow) * 32 + swz;
        half8 ah[4], bh[4];
        #pragma unroll
        for (int mt = 0; mt < 4; ++mt) ah[mt] = *(const half8*)(pA + mt * 512);
        #pragma unroll
        for (int nt = 0; nt < 4; ++nt) bh[nt] = *(const half8*)(pB + nt * 512);
        #pragma unroll
        for (int mt = 0; mt < 4; ++mt)
            #pragma unroll
            for (int nt = 0; nt < 4; ++nt)
                acc[mt][nt] = __builtin_amdgcn_mfma_f32_16x16x32_f16(
                    ah[mt], bh[nt], acc[mt][nt], 0, 0, 0);
    }

    // epilogue: C[row][col]; col = lane&15 within 16-tile, row = quad*4 + r
    const int row_base = blockIdx.y * BM + wm * 64;
    const int col_base = blockIdx.x * BN + wn * 64;
    #pragma unroll
    for (int mt = 0; mt < 4; ++mt)
        #pragma unroll
        for (int nt = 0; nt < 4; ++nt)
            #pragma unroll
            for (int r = 0; r < 4; ++r) {
                const int row = row_base + mt * 16 + quad * 4 + r;
                const int col = col_base + nt * 16 + lrow;
                const float v = acc[mt][nt][r];
                if (EPI == 1) {
                    const float val = v + bias[col];
                    const long idx = (long)row * 320 + (col >> 1);
                    if (col & 1) ((__half*)C2)[idx] = __float2half(val);
                    else         ((__half*)C)[idx]  = __float2half(val);
                } else if (EPI == 2) {
                    ((__half*)C)[(long)row * ldc + col] = __float2half(v);
                } else if (EPI == 3) {
                    ((float*)C)[bz * sC + (long)row * ldc + col] = v + bias[col];
                } else {  // EPI == 4
                    ((__half*)C)[bz * sC + (long)row * ldc + col] =
                        __float2half(alpha * v);
                }
            }
}

// ---- fused prep: h->fp16 (blocks 0..2559) | Wqk^T (2560..2759) |
//      weight^T (2760..2859). One launch instead of three. ------------------
__global__ __launch_bounds__(256) void prep_all(
    const float* __restrict__ h, ushort4* __restrict__ h16,
    const float* __restrict__ Wqk, __half* __restrict__ WqkT,
    const float* __restrict__ weight, __half* __restrict__ wTp)
{
    const int bx = blockIdx.x;
    if (bx < 2560) {
        const int i = bx * 256 + threadIdx.x;
        const float4 v = ((const float4*)h)[i];
        ushort4 o;
        o.x = __half_as_ushort(__float2half(v.x));
        o.y = __half_as_ushort(__float2half(v.y));
        o.z = __half_as_ushort(__float2half(v.z));
        o.w = __half_as_ushort(__float2half(v.w));
        h16[i] = o;
        return;
    }
    __shared__ float t[32][33];
    const float* src;
    __half* dst;
    int ldS, ldT, c0, r0;
    if (bx < 2760) {
        const int b = bx - 2560;           // 20 x 10 tiles of Wqk [320][640]
        src = Wqk; dst = WqkT; ldS = 640; ldT = 320;
        c0 = (b % 20) * 32; r0 = (b / 20) * 32;
    } else {
        const int b = bx - 2760;           // 10 x 10 tiles of weight [320][320]
        src = weight; dst = wTp; ldS = 320; ldT = 320;
        c0 = (b % 10) * 32; r0 = (b / 10) * 32;
    }
    const int lx = threadIdx.x & 31, ly = threadIdx.x >> 5;
    #pragma unroll
    for (int i = 0; i < 4; ++i)
        t[ly + 8 * i][lx] = src[(long)(r0 + ly + 8 * i) * ldS + c0 + lx];
    __syncthreads();
    #pragma unroll
    for (int i = 0; i < 4; ++i)
        dst[(long)(c0 + ly + 8 * i) * ldT + r0 + lx] = __float2half(t[lx][ly + 8 * i]);
}

// ---------------------------------------------------------------------------
// Exact 171st-largest per row of 1024 fp16 values: 2-pass radix select on
// 16-bit order-preserving keys. One wave per row (4 rows / block).
// ---------------------------------------------------------------------------
__global__ __launch_bounds__(256) void topk_softmax(const __half* __restrict__ at,
                                                    __half* __restrict__ attn)
{
    __shared__ int hist[4][256];
    const int lane = threadIdx.x & 63;
    const int wave = threadIdx.x >> 6;
    const long row = (long)blockIdx.x * 4 + wave;

    unsigned short vs[16];
    {
        const uint4* p = (const uint4*)(at + row * 1024 + lane * 16);
        *(uint4*)&vs[0] = p[0];
        *(uint4*)&vs[8] = p[1];
    }

    unsigned key[16];
    #pragma unroll
    for (int i = 0; i < 16; ++i) {
        const unsigned u = vs[i];
        key[i] = (u & 0x8000u) ? ((~u) & 0xFFFFu) : (u | 0x8000u);
    }

    unsigned prefix = 0, pmask = 0;
    int kk = 171;

    #pragma unroll
    for (int pass = 0; pass < 2; ++pass) {
        const int shift = 8 - 8 * pass;
        *(int4*)&hist[wave][lane * 4] = make_int4(0, 0, 0, 0);
        __syncthreads();
        #pragma unroll
        for (int i = 0; i < 16; ++i) {
            if ((key[i] & pmask) == prefix)
                atomicAdd(&hist[wave][(key[i] >> shift) & 255], 1);
        }
        __syncthreads();
        const int4 hh = *(const int4*)&hist[wave][lane * 4];
        const int s = hh.x + hh.y + hh.z + hh.w;
        int suf = s;
        #pragma unroll
        for (int off = 1; off < 64; off <<= 1) {
            const int o = __shfl_down(suf, off);
            if (lane + off < 64) suf += o;
        }
        const int cgt3 = suf - s;
        const int cgt2 = cgt3 + hh.w;
        const int cgt1 = cgt2 + hh.z;
        const int cgt0 = cgt1 + hh.y;
        int pick = 0x7FFFFFFF;
        if (cgt3 < kk && kk <= cgt3 + hh.w) pick = ((4 * lane + 3) << 16) | (kk - cgt3);
        if (cgt2 < kk && kk <= cgt2 + hh.z) pick = ((4 * lane + 2) << 16) | (kk - cgt2);
        if (cgt1 < kk && kk <= cgt1 + hh.y) pick = ((4 * lane + 1) << 16) | (kk - cgt1);
        if (cgt0 < kk && kk <= cgt0 + hh.x) pick = ((4 * lane + 0) << 16) | (kk - cgt0);
        #pragma unroll
        for (int off = 32; off > 0; off >>= 1) pick = min(pick, __shfl_xor(pick, off));
        const unsigned digit = (unsigned)(pick >> 16);
        kk = pick & 0xFFFF;
        prefix |= digit << shift;
        pmask  |= 0xFFu << shift;
        if (pass == 0) __syncthreads();
    }

    const unsigned short tu = (prefix & 0x8000u) ? (unsigned short)(prefix & 0x7FFFu)
                                                 : (unsigned short)((~prefix) & 0xFFFFu);
    const float thr = __half2float(__ushort_as_half(tu));

    float lg[16];
    float mx = -3.4e38f;
    #pragma unroll
    for (int i = 0; i < 16; ++i) {
        const float v = __half2float(__ushort_as_half(vs[i]));
        const float a = (v < thr) ? -1e-7f : v;
        lg[i] = a * (1.0f / 0.3f);
        mx = fmaxf(mx, lg[i]);
    }
    #pragma unroll
    for (int off = 32; off > 0; off >>= 1) mx = fmaxf(mx, __shfl_xor(mx, off));

    float e[16];
    float sum = 0.f;
    #pragma unroll
    for (int i = 0; i < 16; ++i) { e[i] = __expf(lg[i] - mx); sum += e[i]; }
    #pragma unroll
    for (int off = 32; off > 0; off >>= 1) sum += __shfl_xor(sum, off);
    const float inv = 1.0f / sum;

    unsigned short os[16];
    #pragma unroll
    for (int i = 0; i < 16; ++i) os[i] = __half_as_ushort(__float2half(e[i] * inv));
    uint4* q = (uint4*)(attn + row * 1024 + lane * 16);
    q[0] = *(const uint4*)&os[0];
    q[1] = *(const uint4*)&os[8];
}

extern "C" void kernel_launch(void* const* d_in, const int* in_sizes, int n_in,
                              void* d_out, int out_size, void* d_ws, size_t ws_size,
                              hipStream_t stream) {
    (void)in_sizes; (void)n_in; (void)out_size; (void)ws_size;

    const float* h      = (const float*)d_in[0];  // 8x1024x320
    const float* Wqk    = (const float*)d_in[1];  // 320x640
    const float* bqk    = (const float*)d_in[2];  // 640
    const float* weight = (const float*)d_in[3];  // 320x320
    const float* bias   = (const float*)d_in[4];  // 320
    float* out = (float*)d_out;                   // 8192x320

    // workspace layout
    char* p = (char*)d_ws;
    __half* at   = (__half*)p; p += 8388608L * 2;        // 16 MB
    __half* attn = (__half*)p; p += 8388608L * 2;        // 16 MB
    __half* h16  = (__half*)p; p += 2621440L * 2;        // 5 MB
    __half* Q    = (__half*)p; p += 2621440L * 2;        // 5 MB
    __half* Kb   = (__half*)p; p += 2621440L * 2;        // 5 MB
    __half* WqkT = (__half*)p; p += 640L * 320 * 2;      // 400 KB
    __half* wTp  = (__half*)p; p += 384L * 320 * 2;      // padded to 384 rows
    __half* hWT  = (__half*)p; p += 384L * 8192 * 2;     // 6 MB (384 rows incl pad)

    // --- prep (single launch): h->fp16, WqkT, wTp ---
    prep_all<<<2860, 256, 0, stream>>>(h, (ushort4*)h16, Wqk, WqkT, weight, wTp);

    // --- hWT = wTp @ h16^T : [384pad][320] x [8192][320]^T -> fp16 [384][8192]
    gemm_nt<2, 2, 2><<<dim3(64, 3, 1), 256, 0, stream>>>(
        wTp, h16, hWT, nullptr, nullptr,
        320, 320, 320, 8192, 0, 0, 0, 1.0f);

    // --- G1': qk = h16 @ WqkT^T + bqk -> Q,K fp16 (deinterleave) ---
    gemm_nt<4, 1, 1><<<dim3(10, 32, 1), 256, 0, stream>>>(
        h16, WqkT, Q, Kb, bqk,
        320, 320, 320, 0, 0, 0, 0, 1.0f);

    // --- G2: at = 0.125 * Q@K^T (fp16 out) ---
    gemm_nt<2, 2, 4><<<dim3(8, 8, 8), 256, 0, stream>>>(
        Q, Kb, at, nullptr, nullptr,
        320, 320, 320, 1024, 327680, 327680, 1048576, 0.125f);

    // --- topk + softmax -> attn (fp16); one wave per row ---
    topk_softmax<<<2048, 256, 0, stream>>>(at, attn);

    // --- G4': out = attn @ hWT^T + bias (fp32); per-batch M=1024 -> grid y=4
    gemm_nt<4, 1, 3><<<dim3(5, 4, 8), 256, 0, stream>>>(
        attn, hWT, out, nullptr, bias,
        1024, 1024, 8192, 320, 1048576, 1024, 327680, 1.0f);
}